// Round 17
// baseline (123.484 us; speedup 1.0000x reference)
//
#include <hip/hip_runtime.h>
#include <hip/hip_bf16.h>
#include <hip/hip_cooperative_groups.h>
#include <math.h>

namespace cg = cooperative_groups;

#define DIMS 1024
#define NHEADS 16
#define HDIM 64
#define NFEAT 128
#define BB 2
#define NN 1024
#define BN (BB*NN)   // 2048
#define NCH 16       // chunks per (b,h)
#define CSZ 64       // chunk size
#define WW (DIMS*DIMS)
#define QKVN (3*DIMS) // 3072

#define SCALE 0.3535533905932738f       // 64^-0.25
#define INV_SQRT_M 0.08838834764831845f // 1/sqrt(128)

typedef __attribute__((ext_vector_type(8))) _Float16 h8v;  // 8 fp16 (4 VGPRs)
typedef __attribute__((ext_vector_type(8))) short s8v;     // raw 16B
typedef __attribute__((ext_vector_type(4))) float f4v;     // mfma accumulator

__device__ __forceinline__ ushort f2h(float x) {
    _Float16 h = (_Float16)x;
    return *(ushort*)&h;
}
__device__ __forceinline__ float h2f(ushort u) {
    _Float16 h = *(_Float16*)&u;
    return (float)h;
}
__device__ __forceinline__ void gload16(const void* g, void* l) {
    __builtin_amdgcn_global_load_lds(
        (const __attribute__((address_space(1))) unsigned int*)g,
        (__attribute__((address_space(3))) unsigned int*)l,
        16, 0, 0);
}

// ---------------- fused cast f32 -> fp16 for x, Wq,k,v, Wo, omega ----------------
#define NX (BN*DIMS/8)   // 262144
#define NW (WW/8)        // 131072
#define NOM (NFEAT*HDIM/8) // 1024
__global__ __launch_bounds__(256) void cast_all(const float* __restrict__ x,
                                                const float* __restrict__ Wq,
                                                const float* __restrict__ Wk,
                                                const float* __restrict__ Wv,
                                                const float* __restrict__ Wo,
                                                const float* __restrict__ omega,
                                                ushort* __restrict__ xh,
                                                ushort* __restrict__ wqkvh,
                                                ushort* __restrict__ woh,
                                                ushort* __restrict__ omh) {
    const int i = blockIdx.x * 256 + threadIdx.x;
    const float* src; ushort* dst; int off;
    if (i < NX)               { src = x;     dst = xh;                     off = i; }
    else if (i < NX + NW)     { src = Wq;    dst = wqkvh;                  off = i - NX; }
    else if (i < NX + 2 * NW) { src = Wk;    dst = wqkvh + WW;             off = i - NX - NW; }
    else if (i < NX + 3 * NW) { src = Wv;    dst = wqkvh + 2 * (size_t)WW; off = i - NX - 2 * NW; }
    else if (i < NX + 4 * NW) { src = Wo;    dst = woh;                    off = i - NX - 3 * NW; }
    else                      { src = omega; dst = omh;                    off = i - NX - 4 * NW; }
    float4 a = ((const float4*)src)[2 * (size_t)off];
    float4 b = ((const float4*)src)[2 * (size_t)off + 1];
    float v[8] = {a.x, a.y, a.z, a.w, b.x, b.y, b.z, b.w};
    ushort h8[8];
    #pragma unroll
    for (int j = 0; j < 8; ++j) h8[j] = f2h(v[j]);
    *(s8v*)&dst[(size_t)off * 8] = *(s8v*)&h8[0];
}

// ---------------- MFMA GEMM NT; BK=64, swizzled LDS, double-buffered pipeline ----------------
template<int BM, bool HOUT>
__global__ __launch_bounds__(256) void gemm_nt_lds(const ushort* __restrict__ A,
                                                   const ushort* __restrict__ B,
                                                   float* __restrict__ C,
                                                   ushort* __restrict__ C16,
                                                   const float* __restrict__ bias,
                                                   int M, int N, int K, int nbx) {
    constexpr int MF = BM / 32;
    constexpr int AI = BM / 32;
    __shared__ __attribute__((aligned(16))) ushort lA[2][BM][64];
    __shared__ __attribute__((aligned(16))) ushort lB[2][128][64];
    const int tid = threadIdx.x;
    const int w = tid >> 6, l = tid & 63, lr = l & 15, lg = l >> 4;
    const int wm = (w >> 1) * (BM / 2), wn = (w & 1) * 64;
    const int nwg = gridDim.x;
    const int q8 = nwg >> 3;
    const int neu = (blockIdx.x & 7) * q8 + (blockIdx.x >> 3);
    const int bx = neu % nbx, by = neu / nbx;
    const int bi = bx * BM, bj = by * 128;
    const int srow = l >> 3;
    const int scol = ((l & 7) ^ (l >> 3)) * 8;

    f4v acc[MF][4] = {};

    auto STAGE = [&](int buf, int k0) {
        #pragma unroll
        for (int i = 0; i < AI; ++i) {
            const int r0 = w * (8 * AI) + i * 8;
            gload16(&A[(size_t)(bi + r0 + srow) * K + k0 + scol], &lA[buf][r0][0]);
        }
        #pragma unroll
        for (int i = 0; i < 4; ++i) {
            const int r0 = w * 32 + i * 8;
            gload16(&B[(size_t)(bj + r0 + srow) * K + k0 + scol], &lB[buf][r0][0]);
        }
    };
    auto COMPUTE = [&](int buf) {
        #pragma unroll
        for (int kk = 0; kk < 2; ++kk) {
            const int soff = ((kk * 4 + lg) ^ (lr & 7)) * 8;
            h8v b_[4];
            #pragma unroll
            for (int j = 0; j < 4; ++j) b_[j] = *(h8v*)&lB[buf][wn + j * 16 + lr][soff];
            #pragma unroll
            for (int i = 0; i < MF; ++i) {
                h8v a_ = *(h8v*)&lA[buf][wm + i * 16 + lr][soff];
                #pragma unroll
                for (int j = 0; j < 4; ++j)
                    acc[i][j] = __builtin_amdgcn_mfma_f32_16x16x32_f16(a_, b_[j], acc[i][j], 0, 0, 0);
            }
        }
    };

    STAGE(0, 0);
    __syncthreads();
    int cur = 0;
    for (int k0 = 64; k0 < K; k0 += 64) {
        STAGE(cur ^ 1, k0);
        COMPUTE(cur);
        __syncthreads();
        cur ^= 1;
    }
    COMPUTE(cur);

    #pragma unroll
    for (int i = 0; i < MF; ++i)
        #pragma unroll
        for (int j = 0; j < 4; ++j)
            #pragma unroll
            for (int rg = 0; rg < 4; ++rg) {
                const int row = bi + wm + i * 16 + lg * 4 + rg;
                const int col = bj + wn + j * 16 + lr;
                if (HOUT) {
                    C16[(size_t)row * N + col] = f2h(acc[i][j][rg]);
                } else {
                    float r = acc[i][j][rg] + bias[col];
                    C[(size_t)row * N + col] = r;
                }
            }
}

// ---------------- cooperative: stats phase + grid.sync + scan phase ----------------
// grid (32 = b*16+c, NHEADS) = 512 blocks; __launch_bounds__(256,2) forces <=128 VGPR
// so 2 blocks/CU x 256 CU = 512 resident (LDS 74.8 KB <= 80 KB/block). lvt, p, omega
// persist in LDS across grid.sync(); no vt global buffer, no k-phi recompute.
__global__ __launch_bounds__(256, 2) void stats_scan(const ushort* __restrict__ qkvh,
                                                     const ushort* __restrict__ omh,
                                                     float* __restrict__ blockmax,
                                                     ushort* __restrict__ ssum16,
                                                     float* __restrict__ kcsum,
                                                     float* __restrict__ vsum,
                                                     ushort* __restrict__ att_h) {
    __shared__ __attribute__((aligned(16))) ushort pool[36352];
    ushort (*ktile)[72] = (ushort(*)[72])&pool[0];       // k tile (stats)
    ushort (*lv)[72]    = (ushort(*)[72])&pool[4608];    // V rows (stats)
    ushort*  p_lk       = &pool[0];                      // [64][136] p; later phik (overlays ktile+lv)
    ushort (*lktT)[72]  = (ushort(*)[72])&pool[8704];    // p^T (stats)
    ushort*  lq_p       = &pool[8704];                   // [64][136] phiq (scan, overlays lktT)
    ushort*  lom        = &pool[17920];                  // omega [128]*72 (persists into scan q-MFMA)
    ushort*  lsp_p      = &pool[17920];                  // [64][136] Spre (scan, overlays omega)
    ushort (*lvt)[72]   = (ushort(*)[72])&pool[27136];   // V^T (PERSISTS across grid.sync)
    ushort (*qtile)[72] = (ushort(*)[72])&pool[31744];   // q tile (scan)
    ushort (*lA)[72]    = (ushort(*)[72])&pool[31744];   // masked A (overlays qtile)
    __shared__ float kc[NFEAT];
    __shared__ float zin[64];
    __shared__ float zp[4][64];
    __shared__ float gred[4];
    __shared__ float lnorm[64];
    __shared__ float wred[4];

    const int tid = threadIdx.x;
    const int w = tid >> 6, l = tid & 63, lr = l & 15, lg = l >> 4;
    const int h = blockIdx.y;
    const int bxc = blockIdx.x;          // b*16 + c
    const int b = bxc >> 4, c = bxc & 15;
    const int bh = b * NHEADS + h;
    const int n0 = c * CSZ;
    const size_t rowbase = (size_t)b * NN + n0;
    const float hs2 = 0.5f * SCALE * SCALE;

    // ======== STATS PHASE ========
    {   // k tile + per-row |k|^2
        const int r = tid >> 2, c0 = (tid & 3) * 16;
        const size_t g = (rowbase + r) * QKVN + DIMS + h * HDIM + c0;
        s8v v0 = *(const s8v*)&qkvh[g];
        s8v v1 = *(const s8v*)&qkvh[g + 8];
        *(s8v*)&ktile[r][c0] = v0;
        *(s8v*)&ktile[r][c0 + 8] = v1;
        float p = 0.f;
        #pragma unroll
        for (int j = 0; j < 8; ++j) {
            float a = h2f(((ushort*)&v0)[j]); p += a * a;
            float bb2 = h2f(((ushort*)&v1)[j]); p += bb2 * bb2;
        }
        p += __shfl_xor(p, 1); p += __shfl_xor(p, 2);
        if ((tid & 3) == 0) lnorm[r] = p;
    }
    {   // omega
        const int m = tid >> 1, c0 = (tid & 1) * 32;
        #pragma unroll
        for (int i = 0; i < 4; ++i)
            *(s8v*)&lom[m * 72 + c0 + i * 8] = *(const s8v*)&omh[m * HDIM + c0 + i * 8];
    }
    {   // V rows
        const int r = tid >> 2, c0 = (tid & 3) * 16;
        const size_t g = (rowbase + r) * QKVN + 2 * DIMS + h * HDIM + c0;
        *(s8v*)&lv[r][c0]     = *(const s8v*)&qkvh[g];
        *(s8v*)&lv[r][c0 + 8] = *(const s8v*)&qkvh[g + 8];
    }
    __syncthreads();   // S0

    {   // lv -> lvt (persisted)
        const int d = tid >> 2, s0 = (tid & 3) * 16;
        ushort tp[16];
        #pragma unroll
        for (int i = 0; i < 16; ++i) tp[i] = lv[s0 + i][d];
        *(s8v*)&lvt[d][s0] = *(s8v*)&tp[0];
        *(s8v*)&lvt[d][s0 + 8] = *(s8v*)&tp[8];
    }
    float lvv[4][8];
    {   // k-MFMA -> logits
        f4v acc[8] = {};
        #pragma unroll
        for (int k0 = 0; k0 < 64; k0 += 32) {
            h8v a = *(h8v*)&ktile[w * 16 + lr][k0 + lg * 8];
            #pragma unroll
            for (int ct = 0; ct < 8; ++ct) {
                h8v bo = *(h8v*)&lom[(ct * 16 + lr) * 72 + k0 + lg * 8];
                acc[ct] = __builtin_amdgcn_mfma_f32_16x16x32_f16(a, bo, acc[ct], 0, 0, 0);
            }
        }
        float bmax = -3.4e38f;
        #pragma unroll
        for (int rg = 0; rg < 4; ++rg) {
            const int row = w * 16 + lg * 4 + rg;
            const float nh = hs2 * lnorm[row];
            #pragma unroll
            for (int ct = 0; ct < 8; ++ct) {
                lvv[rg][ct] = SCALE * acc[ct][rg] - nh;
                bmax = fmaxf(bmax, lvv[rg][ct]);
            }
        }
        #pragma unroll
        for (int o = 32; o >= 1; o >>= 1) bmax = fmaxf(bmax, __shfl_xor(bmax, o));
        if (l == 0) wred[w] = bmax;
    }
    __syncthreads();   // S1: ktile/lv reads done; wred ready

    const float bm = fmaxf(fmaxf(wred[0], wred[1]), fmaxf(wred[2], wred[3]));
    if (tid == 0) blockmax[h * 32 + bxc] = bm;
    #pragma unroll
    for (int rg = 0; rg < 4; ++rg) {
        const int row = w * 16 + lg * 4 + rg;
        #pragma unroll
        for (int ct = 0; ct < 8; ++ct)
            p_lk[row * 136 + ct * 16 + lr] = f2h(expf(lvv[rg][ct] - bm));
    }
    __syncthreads();   // S2: p ready

    {   // p^T -> lktT
        const int m = tid >> 1, nh2 = (tid & 1) * 32;
        ushort tp[32];
        #pragma unroll
        for (int i = 0; i < 32; ++i) tp[i] = p_lk[(nh2 + i) * 136 + m];
        #pragma unroll
        for (int i = 0; i < 4; ++i) *(s8v*)&lktT[m][nh2 + i * 8] = *(s8v*)&tp[i * 8];
    }
    if (tid < 64) {
        float s = 0.f;
        #pragma unroll 8
        for (int i = 0; i < 64; ++i) s += h2f(lvt[tid][i]);
        vsum[((size_t)bh * NCH + c) * HDIM + tid] = s;
    }
    __syncthreads();   // S3: lktT ready

    {   // ssum_raw[d][m] = sum_n V[n,d]*p[n,m]
        f4v ac2[8] = {};
        #pragma unroll
        for (int k0 = 0; k0 < 64; k0 += 32) {
            h8v a = *(h8v*)&lvt[w * 16 + lr][k0 + lg * 8];
            #pragma unroll
            for (int ct = 0; ct < 8; ++ct) {
                h8v bf = *(h8v*)&lktT[ct * 16 + lr][k0 + lg * 8];
                ac2[ct] = __builtin_amdgcn_mfma_f32_16x16x32_f16(a, bf, ac2[ct], 0, 0, 0);
            }
        }
        const size_t obase = ((size_t)bh * NCH + c) * (HDIM * NFEAT);
        #pragma unroll
        for (int ct = 0; ct < 8; ++ct)
            #pragma unroll
            for (int rg = 0; rg < 4; ++rg) {
                const int d = w * 16 + lg * 4 + rg, m = ct * 16 + lr;
                ssum16[obase + (size_t)d * NFEAT + m] = f2h(ac2[ct][rg]);
            }
        if (tid < 128) {
            float s = 0.f;
            #pragma unroll 8
            for (int i = 0; i < 64; ++i) s += h2f(lktT[tid][i]);
            kcsum[((size_t)bh * NCH + c) * NFEAT + tid] = s;
        }
    }

    cg::this_grid().sync();

    // ======== SCAN PHASE ======== (lvt, p, omega persist in LDS)
    {   // gmax partial
        float mxv = fmaxf(blockmax[tid], blockmax[tid + 256]);
        #pragma unroll
        for (int o = 32; o >= 1; o >>= 1) mxv = fmaxf(mxv, __shfl_xor(mxv, o));
        if (l == 0) gred[w] = mxv;
    }
    {   // q tile + per-row |q|^2
        const int r = tid >> 2, c0 = (tid & 3) * 16;
        const size_t g = (rowbase + r) * QKVN + h * HDIM + c0;
        s8v v0 = *(const s8v*)&qkvh[g];
        s8v v1 = *(const s8v*)&qkvh[g + 8];
        *(s8v*)&qtile[r][c0] = v0;
        *(s8v*)&qtile[r][c0 + 8] = v1;
        float p = 0.f;
        #pragma unroll
        for (int j = 0; j < 8; ++j) {
            float a = h2f(((ushort*)&v0)[j]); p += a * a;
            float bb2 = h2f(((ushort*)&v1)[j]); p += bb2 * bb2;
        }
        p += __shfl_xor(p, 1); p += __shfl_xor(p, 2);
        if ((tid & 3) == 0) lnorm[r] = p;
    }
    __syncthreads();   // S4

    const float gm = fmaxf(fmaxf(gred[0], gred[1]), fmaxf(gred[2], gred[3]));
    const float fac = expf(blockmax[h * 32 + bxc] - gm) * INV_SQRT_M;

    {   // q-MFMA -> phiq into lq (lktT slot)
        f4v acc[8] = {};
        #pragma unroll
        for (int k0 = 0; k0 < 64; k0 += 32) {
            h8v a = *(h8v*)&qtile[w * 16 + lr][k0 + lg * 8];
            #pragma unroll
            for (int ct = 0; ct < 8; ++ct) {
                h8v bo = *(h8v*)&lom[(ct * 16 + lr) * 72 + k0 + lg * 8];
                acc[ct] = __builtin_amdgcn_mfma_f32_16x16x32_f16(a, bo, acc[ct], 0, 0, 0);
            }
        }
        #pragma unroll
        for (int rg = 0; rg < 4; ++rg) {
            const int row = w * 16 + lg * 4 + rg;
            const float nh = hs2 * lnorm[row];
            float lw[8];
            float mx = -3.4e38f;
            #pragma unroll
            for (int ct = 0; ct < 8; ++ct) {
                lw[ct] = SCALE * acc[ct][rg] - nh;
                mx = fmaxf(mx, lw[ct]);
            }
            #pragma unroll
            for (int o = 8; o >= 1; o >>= 1) mx = fmaxf(mx, __shfl_xor(mx, o));
            #pragma unroll
            for (int ct = 0; ct < 8; ++ct)
                lq_p[row * 136 + ct * 16 + lr] = f2h(expf(lw[ct] - mx) * INV_SQRT_M + 1e-4f);
        }
    }
    {   // p -> phik in place: lk = p*fac + 1e-4 (each thread owns its 32 elements)
        const int r = tid >> 2, c0 = (tid & 3) * 32;
        #pragma unroll
        for (int i = 0; i < 32; ++i) {
            const int off = r * 136 + c0 + i;
            p_lk[off] = f2h(h2f(p_lk[off]) * fac + 1e-4f);
        }
    }
    __syncthreads();   // S5: lq, lk ready; omega/qtile dead

    {   // inline prefix: lsp (omega slot) = sum_{c'<c} fac_c'*ssum_raw + 1e-4*vsum
        const int d = tid >> 2;
        const int m0 = (tid & 3) * 32;
        float acc[32] = {};
        float vs_tot = 0.f;
        for (int cp = 0; cp < c; ++cp) {
            const float facp = expf(blockmax[h * 32 + b * 16 + cp] - gm) * INV_SQRT_M;
            vs_tot += vsum[((size_t)bh * NCH + cp) * HDIM + d];
            const size_t cb = ((size_t)bh * NCH + cp) * (HDIM * NFEAT) + (size_t)d * NFEAT + m0;
            #pragma unroll
            for (int i = 0; i < 4; ++i) {
                s8v v = *(const s8v*)&ssum16[cb + i * 8];
                #pragma unroll
                for (int j = 0; j < 8; ++j) acc[i * 8 + j] += facp * h2f(((ushort*)&v)[j]);
            }
        }
        const float vadd = 1e-4f * vs_tot;
        ushort o[32];
        #pragma unroll
        for (int i = 0; i < 32; ++i) o[i] = f2h(acc[i] + vadd);
        #pragma unroll
        for (int i = 0; i < 4; ++i) *(s8v*)&lsp_p[d * 136 + m0 + i * 8] = *(s8v*)&o[i * 8];
    }
    if (tid < NFEAT) {
        float a = 0.f;
        for (int cp = 0; cp < c; ++cp) {
            const float facp = expf(blockmax[h * 32 + b * 16 + cp] - gm) * INV_SQRT_M;
            a += facp * kcsum[((size_t)bh * NCH + cp) * NFEAT + tid] + 64.0f * 1e-4f;
        }
        kc[tid] = a;
    }
    __syncthreads();   // S6: lsp, kc ready

    // Phase 1: A = phiq @ phik^T
    f4v a4[4] = {};
    #pragma unroll
    for (int k0 = 0; k0 < 128; k0 += 32) {
        h8v av = *(h8v*)&lq_p[(w * 16 + lr) * 136 + k0 + lg * 8];
        #pragma unroll
        for (int ct = 0; ct < 4; ++ct) {
            h8v bv = *(h8v*)&p_lk[(ct * 16 + lr) * 136 + k0 + lg * 8];
            a4[ct] = __builtin_amdgcn_mfma_f32_16x16x32_f16(av, bv, a4[ct], 0, 0, 0);
        }
    }
    float zi[4] = {0.f, 0.f, 0.f, 0.f};
    #pragma unroll
    for (int ct = 0; ct < 4; ++ct) {
        #pragma unroll
        for (int rg = 0; rg < 4; ++rg) {
            const int row = w * 16 + lg * 4 + rg;
            const int col = ct * 16 + lr;
            const float val = (col <= row) ? a4[ct][rg] : 0.f;
            const ushort hq = f2h(val);
            zi[rg] += h2f(hq);
            lA[row][col] = hq;
        }
    }
    #pragma unroll
    for (int rg = 0; rg < 4; ++rg) {
        float z = zi[rg];
        z += __shfl_xor(z, 1); z += __shfl_xor(z, 2);
        z += __shfl_xor(z, 4); z += __shfl_xor(z, 8);
        if (lr == 0) zin[w * 16 + lg * 4 + rg] = z;
    }
    {
        const int row = tid & 63, qq = tid >> 6;
        float s = 0.f;
        #pragma unroll 8
        for (int m = 0; m < 32; ++m) s += h2f(lq_p[row * 136 + qq * 32 + m]) * kc[qq * 32 + m];
        zp[qq][row] = s;
    }
    __syncthreads();   // S7

    // Phase 2: out = Amask @ V + phiq @ Spre
    f4v o4[4] = {};
    #pragma unroll
    for (int k0 = 0; k0 < 64; k0 += 32) {
        h8v av = *(h8v*)&lA[w * 16 + lr][k0 + lg * 8];
        #pragma unroll
        for (int ct = 0; ct < 4; ++ct) {
            h8v bv = *(h8v*)&lvt[ct * 16 + lr][k0 + lg * 8];
            o4[ct] = __builtin_amdgcn_mfma_f32_16x16x32_f16(av, bv, o4[ct], 0, 0, 0);
        }
    }
    #pragma unroll
    for (int k0 = 0; k0 < 128; k0 += 32) {
        h8v av = *(h8v*)&lq_p[(w * 16 + lr) * 136 + k0 + lg * 8];
        #pragma unroll
        for (int ct = 0; ct < 4; ++ct) {
            h8v bv = *(h8v*)&lsp_p[(ct * 16 + lr) * 136 + k0 + lg * 8];
            o4[ct] = __builtin_amdgcn_mfma_f32_16x16x32_f16(av, bv, o4[ct], 0, 0, 0);
        }
    }
    #pragma unroll
    for (int rg = 0; rg < 4; ++rg) {
        const int row = w * 16 + lg * 4 + rg;
        const float z = zin[row] + zp[0][row] + zp[1][row] + zp[2][row] + zp[3][row] + 1e-6f;
        const float rz = 1.f / z;
        #pragma unroll
        for (int ct = 0; ct < 4; ++ct) {
            const int d = ct * 16 + lr;
            att_h[(rowbase + row) * DIMS + h * HDIM + d] = f2h(o4[ct][rg] * rz);
        }
    }
}

extern "C" void kernel_launch(void* const* d_in, const int* in_sizes, int n_in,
                              void* d_out, int out_size, void* d_ws, size_t ws_size,
                              hipStream_t stream) {
    const float* x     = (const float*)d_in[0];
    const float* omega = (const float*)d_in[1];
    const float* Wq    = (const float*)d_in[2];
    const float* Wk    = (const float*)d_in[3];
    const float* Wv    = (const float*)d_in[4];
    const float* Wo    = (const float*)d_in[5];
    const float* bo    = (const float*)d_in[6];
    float* out = (float*)d_out;

    const size_t PROJ = (size_t)BN * DIMS;                 // 2M elems
    const size_t PHI  = (size_t)BB * NHEADS * NN * NFEAT;  // 4M elems
    ushort* qkvh    = (ushort*)d_ws;                       // 12 MB
    ushort* xh      = qkvh + (size_t)BN * QKVN;            // 4 MB
    ushort* wqkvh   = xh + PROJ;                           // 6 MB
    ushort* woh     = wqkvh + (size_t)QKVN * DIMS;         // 2 MB
    ushort* omh     = woh + WW;                            // 16 KB
    ushort* ssum16  = omh + NFEAT * HDIM;                  // 8 MB
    ushort* att_hb  = ssum16 + PHI;                        // 4 MB
    float*  kcsum   = (float*)(att_hb + PROJ);             // 256 KB
    float*  blockmax= kcsum + 32 * NCH * NFEAT;            // 512
    float*  vsum    = blockmax + 512;                      // 32*16*64

    // 1: fused casts (x, Wq,k,v, Wo, omega)
    cast_all<<<(NX + 4 * NW + NOM) / 256, 256, 0, stream>>>(x, Wq, Wk, Wv, Wo, omega,
                                                            xh, wqkvh, woh, omh);

    // 2: fused QKV projection -> fp16 [2048 x 3072]; BK=64 dbuf pipeline, 768 blocks
    gemm_nt_lds<64, true><<<(BN / 64) * (QKVN / 128), 256, 0, stream>>>(
        xh, wqkvh, nullptr, qkvh, nullptr, BN, QKVN, DIMS, BN / 64);

    // 3: cooperative stats + scan (512 blocks, 2/CU guaranteed by launch_bounds(256,2))
    {
        void* args[] = {(void*)&qkvh, (void*)&omh, (void*)&blockmax, (void*)&ssum16,
                        (void*)&kcsum, (void*)&vsum, (void*)&att_hb};
        hipLaunchCooperativeKernel((void*)stats_scan, dim3(32, NHEADS), dim3(256),
                                   args, 0, stream);
    }

    // 4: output projection; BM=32 dbuf pipeline -> 512 blocks
    gemm_nt_lds<32, false><<<(BN / 32) * (DIMS / 128), 256, 0, stream>>>(
        att_hb, woh, out, nullptr, bo, BN, DIMS, DIMS, BN / 32);
}

// Round 18
// 79.514 us; speedup vs baseline: 1.5530x; 1.5530x over previous
//
#include <hip/hip_runtime.h>
#include <hip/hip_bf16.h>
#include <math.h>

#define DIMS 1024
#define NHEADS 16
#define HDIM 64
#define NFEAT 128
#define BB 2
#define NN 1024
#define BN (BB*NN)   // 2048
#define NCH 16       // chunks per (b,h)
#define CSZ 64       // chunk size
#define WW (DIMS*DIMS)
#define QKVN (3*DIMS) // 3072

#define SCALE 0.3535533905932738f       // 64^-0.25
#define INV_SQRT_M 0.08838834764831845f // 1/sqrt(128)

typedef __attribute__((ext_vector_type(8))) _Float16 h8v;  // 8 fp16 (4 VGPRs)
typedef __attribute__((ext_vector_type(8))) short s8v;     // raw 16B
typedef __attribute__((ext_vector_type(4))) float f4v;     // mfma accumulator

__device__ __forceinline__ ushort f2h(float x) {
    _Float16 h = (_Float16)x;
    return *(ushort*)&h;
}
__device__ __forceinline__ float h2f(ushort u) {
    _Float16 h = *(_Float16*)&u;
    return (float)h;
}
__device__ __forceinline__ void gload16(const void* g, void* l) {
    __builtin_amdgcn_global_load_lds(
        (const __attribute__((address_space(1))) unsigned int*)g,
        (__attribute__((address_space(3))) unsigned int*)l,
        16, 0, 0);
}

// ---------------- fused cast f32 -> fp16 for x, Wq,k,v, Wo, omega ----------------
#define NX (BN*DIMS/8)   // 262144
#define NW (WW/8)        // 131072
#define NOM (NFEAT*HDIM/8) // 1024
__global__ __launch_bounds__(256) void cast_all(const float* __restrict__ x,
                                                const float* __restrict__ Wq,
                                                const float* __restrict__ Wk,
                                                const float* __restrict__ Wv,
                                                const float* __restrict__ Wo,
                                                const float* __restrict__ omega,
                                                ushort* __restrict__ xh,
                                                ushort* __restrict__ wqkvh,
                                                ushort* __restrict__ woh,
                                                ushort* __restrict__ omh) {
    const int i = blockIdx.x * 256 + threadIdx.x;
    const float* src; ushort* dst; int off;
    if (i < NX)               { src = x;     dst = xh;                     off = i; }
    else if (i < NX + NW)     { src = Wq;    dst = wqkvh;                  off = i - NX; }
    else if (i < NX + 2 * NW) { src = Wk;    dst = wqkvh + WW;             off = i - NX - NW; }
    else if (i < NX + 3 * NW) { src = Wv;    dst = wqkvh + 2 * (size_t)WW; off = i - NX - 2 * NW; }
    else if (i < NX + 4 * NW) { src = Wo;    dst = woh;                    off = i - NX - 3 * NW; }
    else                      { src = omega; dst = omh;                    off = i - NX - 4 * NW; }
    float4 a = ((const float4*)src)[2 * (size_t)off];
    float4 b = ((const float4*)src)[2 * (size_t)off + 1];
    float v[8] = {a.x, a.y, a.z, a.w, b.x, b.y, b.z, b.w};
    ushort h8[8];
    #pragma unroll
    for (int j = 0; j < 8; ++j) h8[j] = f2h(v[j]);
    *(s8v*)&dst[(size_t)off * 8] = *(s8v*)&h8[0];
}

// ---------------- MFMA GEMM NT; BK=64, swizzled LDS, double-buffered 2-phase pipeline ----------
// XCD-bijective 1D grid (nwg % 8 == 0). Swizzle: LDS (row, slot) holds global (row, slot^(row&7)).
// Pipeline: STAGE(next buf) issued BEFORE compute(cur); ONE barrier per K-step.
template<int BM, bool HOUT>
__global__ __launch_bounds__(256) void gemm_nt_lds(const ushort* __restrict__ A,
                                                   const ushort* __restrict__ B,
                                                   float* __restrict__ C,
                                                   ushort* __restrict__ C16,
                                                   const float* __restrict__ bias,
                                                   int M, int N, int K, int nbx) {
    constexpr int MF = BM / 32;
    constexpr int AI = BM / 32;
    __shared__ __attribute__((aligned(16))) ushort lA[2][BM][64];
    __shared__ __attribute__((aligned(16))) ushort lB[2][128][64];
    const int tid = threadIdx.x;
    const int w = tid >> 6, l = tid & 63, lr = l & 15, lg = l >> 4;
    const int wm = (w >> 1) * (BM / 2), wn = (w & 1) * 64;
    const int nwg = gridDim.x;
    const int q8 = nwg >> 3;
    const int neu = (blockIdx.x & 7) * q8 + (blockIdx.x >> 3);
    const int bx = neu % nbx, by = neu / nbx;
    const int bi = bx * BM, bj = by * 128;
    const int srow = l >> 3;
    const int scol = ((l & 7) ^ (l >> 3)) * 8;

    f4v acc[MF][4] = {};

    auto STAGE = [&](int buf, int k0) {
        #pragma unroll
        for (int i = 0; i < AI; ++i) {
            const int r0 = w * (8 * AI) + i * 8;
            gload16(&A[(size_t)(bi + r0 + srow) * K + k0 + scol], &lA[buf][r0][0]);
        }
        #pragma unroll
        for (int i = 0; i < 4; ++i) {
            const int r0 = w * 32 + i * 8;
            gload16(&B[(size_t)(bj + r0 + srow) * K + k0 + scol], &lB[buf][r0][0]);
        }
    };
    auto COMPUTE = [&](int buf) {
        #pragma unroll
        for (int kk = 0; kk < 2; ++kk) {
            const int soff = ((kk * 4 + lg) ^ (lr & 7)) * 8;
            h8v b_[4];
            #pragma unroll
            for (int j = 0; j < 4; ++j) b_[j] = *(h8v*)&lB[buf][wn + j * 16 + lr][soff];
            #pragma unroll
            for (int i = 0; i < MF; ++i) {
                h8v a_ = *(h8v*)&lA[buf][wm + i * 16 + lr][soff];
                #pragma unroll
                for (int j = 0; j < 4; ++j)
                    acc[i][j] = __builtin_amdgcn_mfma_f32_16x16x32_f16(a_, b_[j], acc[i][j], 0, 0, 0);
            }
        }
    };

    STAGE(0, 0);
    __syncthreads();                 // vmcnt(0): buf0 ready
    int cur = 0;
    for (int k0 = 64; k0 < K; k0 += 64) {
        STAGE(cur ^ 1, k0);          // next tile loads in flight under compute
        COMPUTE(cur);
        __syncthreads();             // drains vmcnt (next buf) + lgkm (cur reads)
        cur ^= 1;
    }
    COMPUTE(cur);

    #pragma unroll
    for (int i = 0; i < MF; ++i)
        #pragma unroll
        for (int j = 0; j < 4; ++j)
            #pragma unroll
            for (int rg = 0; rg < 4; ++rg) {
                const int row = bi + wm + i * 16 + lg * 4 + rg;
                const int col = bj + wn + j * 16 + lr;
                if (HOUT) {
                    C16[(size_t)row * N + col] = f2h(acc[i][j][rg]);
                } else {
                    float r = acc[i][j][rg] + bias[col];
                    C[(size_t)row * N + col] = r;
                }
            }
}

// ---------------- phik_stats: k-path phi + chunk stats ----------------
// grid (32 = b*16+c, NHEADS). Emits blockmax, ssum_raw (fp16), kcsum_raw, vsum.
__global__ __launch_bounds__(256) void phik_stats(const ushort* __restrict__ qkvh,
                                                  const ushort* __restrict__ omh,
                                                  float* __restrict__ blockmax,
                                                  ushort* __restrict__ ssum16,
                                                  float* __restrict__ kcsum,
                                                  float* __restrict__ vsum) {
    __shared__ __attribute__((aligned(16))) ushort lq[64][72];
    __shared__ __attribute__((aligned(16))) ushort lom[128 * 72]; // omega; reused as staging [64][136]
    __shared__ __attribute__((aligned(16))) ushort lktT[128][72];
    __shared__ __attribute__((aligned(16))) ushort lv[64][72];
    __shared__ __attribute__((aligned(16))) ushort lvt[64][72];
    __shared__ float lnorm[64];
    __shared__ float wred[4];
    const int tid = threadIdx.x;
    const int h = blockIdx.y;
    const int bn0 = blockIdx.x * 64;
    const int w = tid >> 6, l = tid & 63, lr = l & 15, lg = l >> 4;
    const int b = blockIdx.x >> 4, c = blockIdx.x & 15;
    const int bh = b * NHEADS + h;

    {
        const int r = tid >> 2, c0 = (tid & 3) * 16;
        const size_t g = (size_t)(bn0 + r) * QKVN + DIMS + h * HDIM + c0;  // k at +DIMS
        s8v v0 = *(const s8v*)&qkvh[g];
        s8v v1 = *(const s8v*)&qkvh[g + 8];
        *(s8v*)&lq[r][c0] = v0;
        *(s8v*)&lq[r][c0 + 8] = v1;
        float p = 0.f;
        #pragma unroll
        for (int j = 0; j < 8; ++j) {
            float a = h2f(((ushort*)&v0)[j]); p += a * a;
            float bb2 = h2f(((ushort*)&v1)[j]); p += bb2 * bb2;
        }
        p += __shfl_xor(p, 1); p += __shfl_xor(p, 2);
        if ((tid & 3) == 0) lnorm[r] = p;
    }
    {
        const int m = tid >> 1, c0 = (tid & 1) * 32;
        #pragma unroll
        for (int i = 0; i < 4; ++i)
            *(s8v*)&lom[m * 72 + c0 + i * 8] = *(const s8v*)&omh[m * HDIM + c0 + i * 8];
    }
    {
        const int r = tid >> 2, c0 = (tid & 3) * 16;
        const size_t g = (size_t)(bn0 + r) * QKVN + 2 * DIMS + h * HDIM + c0;
        *(s8v*)&lv[r][c0]     = *(const s8v*)&qkvh[g];
        *(s8v*)&lv[r][c0 + 8] = *(const s8v*)&qkvh[g + 8];
    }
    __syncthreads();

    f4v acc[8] = {};
    #pragma unroll
    for (int k0 = 0; k0 < 64; k0 += 32) {
        h8v a = *(h8v*)&lq[w * 16 + lr][k0 + lg * 8];
        #pragma unroll
        for (int ct = 0; ct < 8; ++ct) {
            h8v bo = *(h8v*)&lom[(ct * 16 + lr) * 72 + k0 + lg * 8];
            acc[ct] = __builtin_amdgcn_mfma_f32_16x16x32_f16(a, bo, acc[ct], 0, 0, 0);
        }
    }

    const float hs2 = 0.5f * SCALE * SCALE;
    float lvv[4][8];
    float bmax = -3.4e38f;
    #pragma unroll
    for (int rg = 0; rg < 4; ++rg) {
        const int row = w * 16 + lg * 4 + rg;
        const float nh = hs2 * lnorm[row];
        #pragma unroll
        for (int ct = 0; ct < 8; ++ct) {
            lvv[rg][ct] = SCALE * acc[ct][rg] - nh;
            bmax = fmaxf(bmax, lvv[rg][ct]);
        }
    }
    #pragma unroll
    for (int o = 32; o >= 1; o >>= 1) bmax = fmaxf(bmax, __shfl_xor(bmax, o));
    if (l == 0) wred[w] = bmax;
    __syncthreads();   // lom (omega) done + wred ready

    const float bm = fmaxf(fmaxf(wred[0], wred[1]), fmaxf(wred[2], wred[3]));
    if (tid == 0) blockmax[h * 32 + blockIdx.x] = bm;
    #pragma unroll
    for (int rg = 0; rg < 4; ++rg) {
        const int row = w * 16 + lg * 4 + rg;
        #pragma unroll
        for (int ct = 0; ct < 8; ++ct)
            lom[row * 136 + ct * 16 + lr] = f2h(expf(lvv[rg][ct] - bm));
    }
    __syncthreads();

    // p^T -> lktT
    {
        const int m = tid >> 1, nh2 = (tid & 1) * 32;
        ushort tp[32];
        #pragma unroll
        for (int i = 0; i < 32; ++i) tp[i] = lom[(nh2 + i) * 136 + m];
        #pragma unroll
        for (int i = 0; i < 4; ++i) *(s8v*)&lktT[m][nh2 + i * 8] = *(s8v*)&tp[i * 8];
    }
    // V^T -> LDS only
    {
        const int d = tid >> 2, s0 = (tid & 3) * 16;
        ushort tp[16];
        #pragma unroll
        for (int i = 0; i < 16; ++i) tp[i] = lv[s0 + i][d];
        *(s8v*)&lvt[d][s0] = *(s8v*)&tp[0];
        *(s8v*)&lvt[d][s0 + 8] = *(s8v*)&tp[8];
    }
    __syncthreads();

    // ssum_raw[d][m] = sum_n V[n,d]*p[n,m]
    f4v ac2[8] = {};
    #pragma unroll
    for (int k0 = 0; k0 < 64; k0 += 32) {
        h8v a = *(h8v*)&lvt[w * 16 + lr][k0 + lg * 8];
        #pragma unroll
        for (int ct = 0; ct < 8; ++ct) {
            h8v bf = *(h8v*)&lktT[ct * 16 + lr][k0 + lg * 8];
            ac2[ct] = __builtin_amdgcn_mfma_f32_16x16x32_f16(a, bf, ac2[ct], 0, 0, 0);
        }
    }
    const size_t obase = ((size_t)bh * NCH + c) * (HDIM * NFEAT);
    #pragma unroll
    for (int ct = 0; ct < 8; ++ct)
        #pragma unroll
        for (int rg = 0; rg < 4; ++rg) {
            const int d = w * 16 + lg * 4 + rg, m = ct * 16 + lr;
            ssum16[obase + (size_t)d * NFEAT + m] = f2h(ac2[ct][rg]);
        }
    if (tid < 128) {
        float s = 0.f;
        #pragma unroll 8
        for (int i = 0; i < 64; ++i) s += h2f(lktT[tid][i]);
        kcsum[((size_t)bh * NCH + c) * NFEAT + tid] = s;
    }
    if (tid < 64) {
        float s = 0.f;
        #pragma unroll 8
        for (int i = 0; i < 64; ++i) s += h2f(lvt[tid][i]);
        vsum[((size_t)bh * NCH + c) * HDIM + tid] = s;
    }
}

// ---------------- scan_final: recomputes phi(q,k) + V^T in-LDS; inline prefix ----------------
// grid (NCH, 32bh). LDS pool with overlays (73.7 KB -> 2 blocks/CU).
__global__ __launch_bounds__(256) void scan_final(const ushort* __restrict__ qkvh,
                                                  const ushort* __restrict__ omh,
                                                  const ushort* __restrict__ ssum16,
                                                  const float* __restrict__ kcsum,
                                                  const float* __restrict__ vsum,
                                                  const float* __restrict__ blockmax,
                                                  ushort* __restrict__ att_h) {
    __shared__ __attribute__((aligned(16))) ushort pool[35840];
    ushort (*lqt)[72]  = (ushort(*)[72]) &pool[0];       // q then k tile; later lA
    ushort*  lom       = &pool[4608];                    // omega; later lsp
    ushort (*lvt)[72]  = (ushort(*)[72]) &pool[13824];
    ushort (*lq)[136]  = (ushort(*)[136])&pool[18432];   // phiq
    ushort (*lk)[136]  = (ushort(*)[136])&pool[27136];   // phik; first 4608 = V-row staging
    ushort (*lv)[72]   = (ushort(*)[72]) &pool[27136];   // V rows overlay (dead before phik)
    ushort (*lA)[72]   = (ushort(*)[72]) &pool[0];       // overlay lqt
    ushort (*lsp)[136] = (ushort(*)[136])&pool[4608];    // overlay lom
    __shared__ float kc[NFEAT];
    __shared__ float zin[64];
    __shared__ float zp[4][64];
    __shared__ float gred[4];
    __shared__ float lnorm[64];
    const int tid = threadIdx.x;
    const int c = blockIdx.x, bh = blockIdx.y;
    const int b = bh >> 4, h = bh & 15;
    const int n0 = c * CSZ;
    const size_t rowbase = (size_t)b * NN + n0;
    const int w = tid >> 6, l = tid & 63, lr = l & 15, lg = l >> 4;

    // gmax partial (gred read after S0)
    {
        float mxv = fmaxf(blockmax[tid], blockmax[tid + 256]);
        #pragma unroll
        for (int o = 32; o >= 1; o >>= 1) mxv = fmaxf(mxv, __shfl_xor(mxv, o));
        if (l == 0) gred[w] = mxv;
    }
    // load q tile + norms, omega, V rows
    {
        const int r = tid >> 2, c0 = (tid & 3) * 16;
        const size_t g = (rowbase + r) * QKVN + h * HDIM + c0;
        s8v v0 = *(const s8v*)&qkvh[g];
        s8v v1 = *(const s8v*)&qkvh[g + 8];
        *(s8v*)&lqt[r][c0] = v0;
        *(s8v*)&lqt[r][c0 + 8] = v1;
        float p = 0.f;
        #pragma unroll
        for (int j = 0; j < 8; ++j) {
            float a = h2f(((ushort*)&v0)[j]); p += a * a;
            float bb2 = h2f(((ushort*)&v1)[j]); p += bb2 * bb2;
        }
        p += __shfl_xor(p, 1); p += __shfl_xor(p, 2);
        if ((tid & 3) == 0) lnorm[r] = p;
    }
    {
        const int m = tid >> 1, c0 = (tid & 1) * 32;
        #pragma unroll
        for (int i = 0; i < 4; ++i)
            *(s8v*)&lom[m * 72 + c0 + i * 8] = *(const s8v*)&omh[m * HDIM + c0 + i * 8];
    }
    {
        const int r = tid >> 2, c0 = (tid & 3) * 16;
        const size_t g = (rowbase + r) * QKVN + 2 * DIMS + h * HDIM + c0;
        *(s8v*)&lv[r][c0]     = *(const s8v*)&qkvh[g];
        *(s8v*)&lv[r][c0 + 8] = *(const s8v*)&qkvh[g + 8];
    }
    __syncthreads();   // S0

    const float gm = fmaxf(fmaxf(gred[0], gred[1]), fmaxf(gred[2], gred[3]));
    const float hs2 = 0.5f * SCALE * SCALE;

    // V^T: lv -> lvt
    {
        const int d = tid >> 2, s0 = (tid & 3) * 16;
        ushort tp[16];
        #pragma unroll
        for (int i = 0; i < 16; ++i) tp[i] = lv[s0 + i][d];
        *(s8v*)&lvt[d][s0] = *(s8v*)&tp[0];
        *(s8v*)&lvt[d][s0 + 8] = *(s8v*)&tp[8];
    }
    // q-MFMA -> phiq into lq
    {
        f4v acc[8] = {};
        #pragma unroll
        for (int k0 = 0; k0 < 64; k0 += 32) {
            h8v a = *(h8v*)&lqt[w * 16 + lr][k0 + lg * 8];
            #pragma unroll
            for (int ct = 0; ct < 8; ++ct) {
                h8v bo = *(h8v*)&lom[(ct * 16 + lr) * 72 + k0 + lg * 8];
                acc[ct] = __builtin_amdgcn_mfma_f32_16x16x32_f16(a, bo, acc[ct], 0, 0, 0);
            }
        }
        #pragma unroll
        for (int rg = 0; rg < 4; ++rg) {
            const int row = w * 16 + lg * 4 + rg;
            const float nh = hs2 * lnorm[row];
            float lvv[8];
            float mx = -3.4e38f;
            #pragma unroll
            for (int ct = 0; ct < 8; ++ct) {
                lvv[ct] = SCALE * acc[ct][rg] - nh;
                mx = fmaxf(mx, lvv[ct]);
            }
            #pragma unroll
            for (int o = 8; o >= 1; o >>= 1) mx = fmaxf(mx, __shfl_xor(mx, o));
            #pragma unroll
            for (int ct = 0; ct < 8; ++ct)
                lq[row][ct * 16 + lr] = f2h(expf(lvv[ct] - mx) * INV_SQRT_M + 1e-4f);
        }
    }
    __syncthreads();   // S1: lqt free for k-tile; lv consumed

    // load k tile + norms
    {
        const int r = tid >> 2, c0 = (tid & 3) * 16;
        const size_t g = (rowbase + r) * QKVN + DIMS + h * HDIM + c0;
        s8v v0 = *(const s8v*)&qkvh[g];
        s8v v1 = *(const s8v*)&qkvh[g + 8];
        *(s8v*)&lqt[r][c0] = v0;
        *(s8v*)&lqt[r][c0 + 8] = v1;
        float p = 0.f;
        #pragma unroll
        for (int j = 0; j < 8; ++j) {
            float a = h2f(((ushort*)&v0)[j]); p += a * a;
            float bb2 = h2f(((ushort*)&v1)[j]); p += bb2 * bb2;
        }
        p += __shfl_xor(p, 1); p += __shfl_xor(p, 2);
        if ((tid & 3) == 0) lnorm[r] = p;
    }
    __syncthreads();   // S2

    // k-MFMA -> phik into lk (overwrites lv staging, dead)
    const float bm = blockmax[h * 32 + b * 16 + c];
    const float fac = expf(bm - gm) * INV_SQRT_M;
    {
        f4v acc[8] = {};
        #pragma unroll
        for (int k0 = 0; k0 < 64; k0 += 32) {
            h8v a = *(h8v*)&lqt[w * 16 + lr][k0 + lg * 8];
            #pragma unroll
            for (int ct = 0; ct < 8; ++ct) {
                h8v bo = *(h8v*)&lom[(ct * 16 + lr) * 72 + k0 + lg * 8];
                acc[ct] = __builtin_amdgcn_mfma_f32_16x16x32_f16(a, bo, acc[ct], 0, 0, 0);
            }
        }
        __syncthreads();   // S3a: everyone's V-row reads & omega reads done before lk write
        #pragma unroll
        for (int rg = 0; rg < 4; ++rg) {
            const int row = w * 16 + lg * 4 + rg;
            const float nh = hs2 * lnorm[row];
            #pragma unroll
            for (int ct = 0; ct < 8; ++ct) {
                const float lv2 = SCALE * acc[ct][rg] - nh;
                lk[row][ct * 16 + lr] = f2h(expf(lv2 - bm) * fac + 1e-4f);
            }
        }
    }
    __syncthreads();   // S3: lk ready; lom/lqt dead -> lsp/lA usable

    // inline prefix: lsp = sum_{c'<c} fac_c'*ssum_raw + 1e-4*vsum ; kc prefix
    {
        const int d = tid >> 2;
        const int m0 = (tid & 3) * 32;
        float acc[32] = {};
        float vs_tot = 0.f;
        for (int cp = 0; cp < c; ++cp) {
            const float facp = expf(blockmax[h * 32 + b * 16 + cp] - gm) * INV_SQRT_M;
            vs_tot += vsum[((size_t)bh * NCH + cp) * HDIM + d];
            const size_t cb = ((size_t)bh * NCH + cp) * (HDIM * NFEAT) + (size_t)d * NFEAT + m0;
            #pragma unroll
            for (int i = 0; i < 4; ++i) {
                s8v v = *(const s8v*)&ssum16[cb + i * 8];
                #pragma unroll
                for (int j = 0; j < 8; ++j) acc[i * 8 + j] += facp * h2f(((ushort*)&v)[j]);
            }
        }
        const float vadd = 1e-4f * vs_tot;
        ushort o[32];
        #pragma unroll
        for (int i = 0; i < 32; ++i) o[i] = f2h(acc[i] + vadd);
        #pragma unroll
        for (int i = 0; i < 4; ++i) *(s8v*)&lsp[d][m0 + i * 8] = *(s8v*)&o[i * 8];
    }
    if (tid < NFEAT) {
        float a = 0.f;
        for (int cp = 0; cp < c; ++cp) {
            const float facp = expf(blockmax[h * 32 + b * 16 + cp] - gm) * INV_SQRT_M;
            a += facp * kcsum[((size_t)bh * NCH + cp) * NFEAT + tid] + 64.0f * 1e-4f;
        }
        kc[tid] = a;
    }
    __syncthreads();   // S4: lsp, kc ready

    // Phase 1: A = phiq @ phik^T
    f4v a4[4] = {};
    #pragma unroll
    for (int k0 = 0; k0 < 128; k0 += 32) {
        h8v av = *(h8v*)&lq[w * 16 + lr][k0 + lg * 8];
        #pragma unroll
        for (int ct = 0; ct < 4; ++ct) {
            h8v bv = *(h8v*)&lk[ct * 16 + lr][k0 + lg * 8];
            a4[ct] = __builtin_amdgcn_mfma_f32_16x16x32_f16(av, bv, a4[ct], 0, 0, 0);
        }
    }
    float zi[4] = {0.f, 0.f, 0.f, 0.f};
    #pragma unroll
    for (int ct = 0; ct < 4; ++ct) {
        #pragma unroll
        for (int rg = 0; rg < 4; ++rg) {
            const int row = w * 16 + lg * 4 + rg;
            const int col = ct * 16 + lr;
            const float val = (col <= row) ? a4[ct][rg] : 0.f;
            const ushort hq = f2h(val);
            zi[rg] += h2f(hq);
            lA[row][col] = hq;
        }
    }
    #pragma unroll
    for (int rg = 0; rg < 4; ++rg) {
        float z = zi[rg];
        z += __shfl_xor(z, 1); z += __shfl_xor(z, 2);
        z += __shfl_xor(z, 4); z += __shfl_xor(z, 8);
        if (lr == 0) zin[w * 16 + lg * 4 + rg] = z;
    }
    {
        const int row = tid & 63, qq = tid >> 6;
        float s = 0.f;
        #pragma unroll 8
        for (int m = 0; m < 32; ++m) s += h2f(lq[row][qq * 32 + m]) * kc[qq * 32 + m];
        zp[qq][row] = s;
    }
    __syncthreads();   // S5

    // Phase 2: out = Amask @ V + phiq @ Spre
    f4v o4[4] = {};
    #pragma unroll
    for (int k0 = 0; k0 < 64; k0 += 32) {
        h8v av = *(h8v*)&lA[w * 16 + lr][k0 + lg * 8];
        #pragma unroll
        for (int ct = 0; ct < 4; ++ct) {
            h8v bv = *(h8v*)&lvt[ct * 16 + lr][k0 + lg * 8];
            o4[ct] = __builtin_amdgcn_mfma_f32_16x16x32_f16(av, bv, o4[ct], 0, 0, 0);
        }
    }
    #pragma unroll
    for (int k0 = 0; k0 < 128; k0 += 32) {
        h8v av = *(h8v*)&lq[w * 16 + lr][k0 + lg * 8];
        #pragma unroll
        for (int ct = 0; ct < 4; ++ct) {
            h8v bv = *(h8v*)&lsp[ct * 16 + lr][k0 + lg * 8];
            o4[ct] = __builtin_amdgcn_mfma_f32_16x16x32_f16(av, bv, o4[ct], 0, 0, 0);
        }
    }
    #pragma unroll
    for (int rg = 0; rg < 4; ++rg) {
        const int row = w * 16 + lg * 4 + rg;
        const float z = zin[row] + zp[0][row] + zp[1][row] + zp[2][row] + zp[3][row] + 1e-6f;
        const float rz = 1.f / z;
        #pragma unroll
        for (int ct = 0; ct < 4; ++ct) {
            const int d = ct * 16 + lr;
            att_h[(rowbase + row) * DIMS + h * HDIM + d] = f2h(o4[ct][rg] * rz);
        }
    }
}

extern "C" void kernel_launch(void* const* d_in, const int* in_sizes, int n_in,
                              void* d_out, int out_size, void* d_ws, size_t ws_size,
                              hipStream_t stream) {
    const float* x     = (const float*)d_in[0];
    const float* omega = (const float*)d_in[1];
    const float* Wq    = (const float*)d_in[2];
    const float* Wk    = (const float*)d_in[3];
    const float* Wv    = (const float*)d_in[4];
    const float* Wo    = (const float*)d_in[5];
    const float* bo    = (const float*)d_in[6];
    float* out = (float*)d_out;

    const size_t PROJ = (size_t)BN * DIMS;                 // 2M elems
    const size_t PHI  = (size_t)BB * NHEADS * NN * NFEAT;  // 4M elems
    ushort* qkvh    = (ushort*)d_ws;                       // 12 MB
    ushort* xh      = qkvh + (size_t)BN * QKVN;            // 4 MB
    ushort* wqkvh   = xh + PROJ;                           // 6 MB
    ushort* woh     = wqkvh + (size_t)QKVN * DIMS;         // 2 MB
    ushort* omh     = woh + WW;                            // 16 KB
    ushort* ssum16  = omh + NFEAT * HDIM;                  // 8 MB
    ushort* att_hb  = ssum16 + PHI;                        // 4 MB
    float*  kcsum   = (float*)(att_hb + PROJ);             // 256 KB
    float*  blockmax= kcsum + 32 * NCH * NFEAT;            // 512
    float*  vsum    = blockmax + 512;                      // 32*16*64

    // 1: fused casts (x, Wq,k,v, Wo, omega)
    cast_all<<<(NX + 4 * NW + NOM) / 256, 256, 0, stream>>>(x, Wq, Wk, Wv, Wo, omega,
                                                            xh, wqkvh, woh, omh);

    // 2: fused QKV projection -> fp16 [2048 x 3072]; BK=64 dbuf pipeline, 768 blocks = 3/CU
    gemm_nt_lds<64, true><<<(BN / 64) * (QKVN / 128), 256, 0, stream>>>(
        xh, wqkvh, nullptr, qkvh, nullptr, BN, QKVN, DIMS, BN / 64);

    // 3: key-path phi + chunk stats (512 blocks)
    dim3 pg(32, NHEADS);
    phik_stats<<<pg, 256, 0, stream>>>(qkvh, omh, blockmax, ssum16, kcsum, vsum);

    // 4: causal attention; recomputes phi(q,k) + V^T per chunk, inline prefix
    dim3 cg(NCH, BB * NHEADS);
    scan_final<<<cg, 256, 0, stream>>>(qkvh, omh, ssum16, kcsum, vsum,
                                       blockmax, att_hb);

    // 5: output projection; BM=32 dbuf pipeline -> 512 blocks = 2/CU
    gemm_nt_lds<32, false><<<(BN / 32) * (DIMS / 128), 256, 0, stream>>>(
        att_hb, woh, out, nullptr, bo, BN, DIMS, DIMS, BN / 32);
}